// Round 8
// baseline (26.147 us; speedup 1.0000x reference)
//
#include <hip/hip_runtime.h>

#define M 128
#define BT 64

typedef _Float16 half8 __attribute__((ext_vector_type(8)));
typedef __fp16 fp16x2 __attribute__((ext_vector_type(2)));
typedef float f32x4 __attribute__((ext_vector_type(4)));

// d_ws float layout (only what consumers actually read):
//   [0    .. 63]    prefix T tables: T_d at ws[2^d], size 2^d, d=0..5 (ws[0] = 0)
//   [3072 .. 3583]  sp/vals/li/ri for generic fallback
//   [4096 .. 5119]  A-fragment buffer: 4 frags x 64 lanes x 16B (f16, MFMA layout)
//
// A-matrix (Bt, 32x64): Bt[prow][i] :=
//   prow 0      -> T6[i]
//   prow 1..2   -> T7[2i+(prow-1)]
//   prow 3..6   -> T8[4i+(prow-3)]
//   prow 7..14  -> T9[8i+(prow-7)]
//   prow 15..30 -> V10[16i+(prow-15)]
//   prow 31     -> 0

__global__ void setup_kernel(const float* __restrict__ spp,
                             const float* __restrict__ vp,
                             const float* __restrict__ Lm,
                             const float* __restrict__ Rm,
                             float* __restrict__ ws) {
  __shared__ float ssp[M], svl[M];
  __shared__ int sli[M], sri[M];
  __shared__ float sT[1024];   // T_d at sT[2^d + i], d=0..9
  __shared__ float sV10[1024]; // V10[i]
  const int t = threadIdx.x;   // 256 threads
  const int w = t >> 6, l = t & 63;

  if (t < M) {
    ssp[t] = 1.f / (1.f + __expf(2.f - 4.f * spp[t]));
    svl[t] = vp[t & 31] * 3.f + 1.f;
  }
  // wave-cooperative coalesced one-hot scan: 256 row-tasks over 4 waves
  for (int task = w; task < 256; task += 4) {
    const int mat = task >> 7, row = task & (M - 1);
    const float* Mt = mat ? Rm : Lm;
    const float v0 = Mt[row * M + l];
    const float v1 = Mt[row * M + 64 + l];
    const unsigned long long b0 = __ballot(v0 > 0.5f);
    const unsigned long long b1 = __ballot(v1 > 0.5f);
    if (l == 0) {
      const int idx = b0 ? (__ffsll((unsigned long long)b0) - 1)
                         : (64 + __ffsll((unsigned long long)b1) - 1);
      if (mat) sri[row] = idx; else sli[row] = idx;
    }
  }
  __syncthreads();
  if (t < M) {
    ws[3072 + t] = ssp[t];
    ws[3200 + t] = svl[t];
    ((int*)ws)[3328 + t] = sli[t];
    ((int*)ws)[3456 + t] = sri[t];
  }
  if (t == 0) { sT[0] = 0.f; sT[1] = ssp[0]; }

  // barrier-free parallel pointer-chase: 4 leaf paths per thread, 4-way ILP.
  // sT[2^d + i] = ssp[node_d(i)], sV10[i] = svl[node_10(i)]; each unique
  // entry written once (by the path whose remaining suffix bits are zero).
  {
    const int p0 = t * 4;
    int nd[4] = {0, 0, 0, 0};
#pragma unroll
    for (int d = 1; d <= 10; ++d) {
#pragma unroll
      for (int pi = 0; pi < 4; ++pi) {
        const int p = p0 + pi;
        const int bit = (p >> (10 - d)) & 1;
        nd[pi] = bit ? sri[nd[pi]] : sli[nd[pi]];
        if (d <= 9) {
          if ((p & ((1 << (10 - d)) - 1)) == 0)
            sT[(1 << d) + (p >> (10 - d))] = ssp[nd[pi]];
        } else {
          sV10[p] = svl[nd[pi]];
        }
      }
    }
  }
  __syncthreads();

  // Build pre-packed f16 A-fragments from LDS. Element e of a lane's 16B frag
  // holds k-local kl = (e<4) ? 4g+e : 16+4g+(e-4); i = ks*32 + kl. The same
  // convention packs the B operand in fractal10, so the HW k-slot mapping
  // cancels regardless of its exact (g,e)->k bijection.
  unsigned* fbout = (unsigned*)(ws + 4096);
  for (int d = t; d < 1024; d += 256) {
    const int dw = d & 3;
    const int lane = (d >> 2) & 63;
    const int rt = d >> 9;
    const int ks = (d >> 8) & 1;
    const int m = lane & 15, gg = lane >> 4;
    const int prow = rt * 16 + m;
    float v[2];
#pragma unroll
    for (int h = 0; h < 2; ++h) {
      const int e = 2 * dw + h;
      const int kl = (e < 4) ? (4 * gg + e) : (16 + 4 * gg + (e - 4));
      const int i = ks * 32 + kl;
      float val;
      if (prow == 0) val = sT[64 + i];
      else if (prow < 3) val = sT[128 + 2 * i + (prow - 1)];
      else if (prow < 7) val = sT[256 + 4 * i + (prow - 3)];
      else if (prow < 15) val = sT[512 + 8 * i + (prow - 7)];
      else if (prow < 31) val = sV10[16 * i + (prow - 15)];
      else val = 0.f;
      v[h] = val;
    }
    union { fp16x2 h; unsigned u; } pu;
    pu.h = __builtin_amdgcn_cvt_pkrtz(v[0], v[1]);
    fbout[d] = pu.u;
  }
  // prefix tables T_0..T_5 for fractal10's register phase
  if (t < 64) ws[t] = sT[t];
}

#define PSTEP(S)                                                              \
  {                                                                           \
    float dot = 0.f;                                                          \
    _Pragma("unroll") for (int i = 0; i < (S); ++i)                           \
        dot = fmaf(c[i], sT[(S) + i], dot);                                   \
    const float sv = fmaf(dot, hi - lo, lo);                                  \
    tt = 1.f / (1.f + __expf((sv - xv) * 10.f));                              \
    uu = 1.f - tt;                                                            \
    const float nlo = fmaf(tt, sv, uu * lo);                                  \
    const float nhi = fmaf(tt, hi, uu * sv);                                  \
    lo = nlo; hi = nhi;                                                       \
    _Pragma("unroll") for (int i = (S)-1; i >= 0; --i) {                      \
      const float v = c[i];                                                   \
      c[2 * i + 1] = v * tt;                                                  \
      c[2 * i] = v * uu;                                                      \
    }                                                                         \
  }

#define SIGSTEP(dotv)                                   \
  {                                                     \
    const float sv = fmaf((dotv), hi - lo, lo);         \
    tt = 1.f / (1.f + __expf((sv - xv) * 10.f));        \
    uu = 1.f - tt;                                      \
    const float nlo = fmaf(tt, sv, uu * lo);            \
    const float nhi = fmaf(tt, hi, uu * sv);            \
    lo = nlo; hi = nhi;                                 \
  }

__launch_bounds__(BT)
__global__ void fractal10(const float* __restrict__ x,
                          const int* __restrict__ dpt,
                          float* __restrict__ out, int n,
                          const float* __restrict__ ws) {
  if (dpt[0] != 10) return;
  __shared__ float sT[64];
  __shared__ __align__(16) float sbuf[64 * 32];  // 8KB: c(f16) then P(f32), per point 128B
  const int l = threadIdx.x;
  const int gid = blockIdx.x * BT + l;

  sT[l] = ws[l];
  const float4* fb = (const float4*)(ws + 4096);
  union f4h8 { float4 f; half8 h; };
  f4h8 A00, A01, A10, A11;
  A00.f = fb[0 * 64 + l];   // rt0 ks0
  A01.f = fb[1 * 64 + l];   // rt0 ks1
  A10.f = fb[2 * 64 + l];   // rt1 ks0
  A11.f = fb[3 * 64 + l];   // rt1 ks1
  const float xv = (gid < n) ? x[gid] : 0.5f;
  __syncthreads();

  float c[64];
  float lo = 0.f, hi = 1.f, tt, uu;
  c[0] = 1.f;
  PSTEP(1) PSTEP(2) PSTEP(4) PSTEP(8) PSTEP(16) PSTEP(32)

  // pack c -> f16, write [point][chunk] with XOR-16B swizzle
  {
    char* cb = (char*)sbuf + l * 128;
#pragma unroll
    for (int q = 0; q < 8; ++q) {
      const int k0 = (q >> 2) * 32 + (q & 3) * 4;
      union { fp16x2 h2[4]; float4 f4; } u;
      u.h2[0] = __builtin_amdgcn_cvt_pkrtz(c[k0], c[k0 + 1]);
      u.h2[1] = __builtin_amdgcn_cvt_pkrtz(c[k0 + 2], c[k0 + 3]);
      u.h2[2] = __builtin_amdgcn_cvt_pkrtz(c[k0 + 16], c[k0 + 17]);
      u.h2[3] = __builtin_amdgcn_cvt_pkrtz(c[k0 + 18], c[k0 + 19]);
      *(float4*)(cb + ((q ^ (l & 7)) * 16)) = u.f4;
    }
  }
  __syncthreads();

  // read B fragments (transposed c)
  half8 bf[2][4];
  const int col = l & 15, g = l >> 4;
#pragma unroll
  for (int ct = 0; ct < 4; ++ct) {
    const int p = 16 * ct + col;
    const char* pb = (const char*)sbuf + p * 128;
#pragma unroll
    for (int ks = 0; ks < 2; ++ks) {
      const int q = ks * 4 + g;
      bf[ks][ct] = *(const half8*)(pb + ((q ^ (p & 7)) * 16));
    }
  }
  __syncthreads();

  // P[32 x 64pts] = Bt(32x64) x C(64x64)
  f32x4 acc[2][4];
#pragma unroll
  for (int rt = 0; rt < 2; ++rt)
#pragma unroll
    for (int ct = 0; ct < 4; ++ct) acc[rt][ct] = f32x4{0.f, 0.f, 0.f, 0.f};
#pragma unroll
  for (int ct = 0; ct < 4; ++ct) {
    acc[0][ct] = __builtin_amdgcn_mfma_f32_16x16x32_f16(A00.h, bf[0][ct], acc[0][ct], 0, 0, 0);
    acc[0][ct] = __builtin_amdgcn_mfma_f32_16x16x32_f16(A01.h, bf[1][ct], acc[0][ct], 0, 0, 0);
    acc[1][ct] = __builtin_amdgcn_mfma_f32_16x16x32_f16(A10.h, bf[0][ct], acc[1][ct], 0, 0, 0);
    acc[1][ct] = __builtin_amdgcn_mfma_f32_16x16x32_f16(A11.h, bf[1][ct], acc[1][ct], 0, 0, 0);
  }

  // scatter P back: D layout col=lane&15, row=(lane>>4)*4+reg (m89-verified)
#pragma unroll
  for (int rt = 0; rt < 2; ++rt)
#pragma unroll
    for (int ct = 0; ct < 4; ++ct) {
      const int p = 16 * ct + col;
      const int rb = rt * 4 + g;
      *(f32x4*)((char*)sbuf + p * 128 + ((rb ^ (p & 7)) * 16)) = acc[rt][ct];
    }
  __syncthreads();
  float4 P[8];
#pragma unroll
  for (int j = 0; j < 8; ++j)
    P[j] = *(const float4*)((const char*)sbuf + l * 128 + ((j ^ (l & 7)) * 16));

  // sequential tail on P: rows 0 | 1..2 | 3..6 | 7..14 | 15..30
  SIGSTEP(P[0].x);
  const float w20 = uu, w21 = tt;
  SIGSTEP(fmaf(w20, P[0].y, w21 * P[0].z));
  float W4[4] = {w20 * uu, w20 * tt, w21 * uu, w21 * tt};
  SIGSTEP(fmaf(W4[0], P[0].w, fmaf(W4[1], P[1].x, fmaf(W4[2], P[1].y, W4[3] * P[1].z))));
  float W8[8];
#pragma unroll
  for (int s = 3; s >= 0; --s) { W8[2 * s + 1] = W4[s] * tt; W8[2 * s] = W4[s] * uu; }
  {
    float d0 = fmaf(W8[0], P[1].w, W8[1] * P[2].x);
    float d1 = fmaf(W8[2], P[2].y, W8[3] * P[2].z);
    float d2 = fmaf(W8[4], P[2].w, W8[5] * P[3].x);
    float d3 = fmaf(W8[6], P[3].y, W8[7] * P[3].z);
    SIGSTEP((d0 + d1) + (d2 + d3));
  }
  float W16[16];
#pragma unroll
  for (int s = 7; s >= 0; --s) { W16[2 * s + 1] = W8[s] * tt; W16[2 * s] = W8[s] * uu; }
  float outv;
  {
    float d0 = fmaf(W16[0], P[3].w, W16[1] * P[4].x);
    d0 = fmaf(W16[2], P[4].y, d0); d0 = fmaf(W16[3], P[4].z, d0);
    float d1 = fmaf(W16[4], P[4].w, W16[5] * P[5].x);
    d1 = fmaf(W16[6], P[5].y, d1); d1 = fmaf(W16[7], P[5].z, d1);
    float d2 = fmaf(W16[8], P[5].w, W16[9] * P[6].x);
    d2 = fmaf(W16[10], P[6].y, d2); d2 = fmaf(W16[11], P[6].z, d2);
    float d3 = fmaf(W16[12], P[6].w, W16[13] * P[7].x);
    d3 = fmaf(W16[14], P[7].y, d3); d3 = fmaf(W16[15], P[7].z, d3);
    outv = (d0 + d1) + (d2 + d3);
  }
  if (gid < n) out[gid] = outv;
}

// Generic-depth fallback (never taken when depth==10; correctness only).
// LDS-backed [node][tid] state, column-per-thread => no scratch, no barriers.
__launch_bounds__(64)
__global__ void fractal_generic(const float* __restrict__ x,
                                const int* __restrict__ dpt,
                                float* __restrict__ out, int n,
                                const float* __restrict__ ws) {
  const int depth = dpt[0];
  if (depth == 10) return;
  __shared__ float w[2][M][64];  // 64KB
  const int t = threadIdx.x;
  const float* sp = ws + 3072;
  const float* vals = ws + 3200;
  const int* li = (const int*)ws + 3328;
  const int* ri = (const int*)ws + 3456;
  for (int gid = blockIdx.x * 64 + t; gid < n; gid += gridDim.x * 64) {
    const float xv = x[gid];
    for (int j = 0; j < M; ++j) w[0][j][t] = 0.f;
    w[0][0][t] = 1.f;
    float lo = 0.f, hi = 1.f;
    int cb = 0;
    for (int k = 0; k < depth; ++k) {
      float dot = 0.f;
      for (int j = 0; j < M; ++j) dot += w[cb][j][t] * sp[j];
      const float sv = lo + dot * (hi - lo);
      const float tt = 1.f / (1.f + __expf((sv - xv) * 10.f));
      const float uu = 1.f - tt;
      for (int j = 0; j < M; ++j) w[cb ^ 1][j][t] = 0.f;
      for (int j = 0; j < M; ++j) {
        const float v = w[cb][j][t];
        w[cb ^ 1][li[j]][t] += uu * v;
        w[cb ^ 1][ri[j]][t] += tt * v;
      }
      const float nlo = uu * lo + tt * sv;
      const float nhi = uu * sv + tt * hi;
      lo = nlo; hi = nhi;
      cb ^= 1;
    }
    float acc = 0.f;
    for (int j = 0; j < M; ++j) acc += w[cb][j][t] * vals[j];
    out[gid] = acc;
  }
}

extern "C" void kernel_launch(void* const* d_in, const int* in_sizes, int n_in,
                              void* d_out, int out_size, void* d_ws, size_t ws_size,
                              hipStream_t stream) {
  const float* x   = (const float*)d_in[0];
  const float* spp = (const float*)d_in[1];
  const float* vp  = (const float*)d_in[2];
  const float* Lm  = (const float*)d_in[3];
  const float* Rm  = (const float*)d_in[4];
  const int* dpt   = (const int*)d_in[5];
  float* out = (float*)d_out;
  float* ws = (float*)d_ws;
  const int n = in_sizes[0];

  hipLaunchKernelGGL(setup_kernel, dim3(1), dim3(256), 0, stream, spp, vp, Lm, Rm, ws);
  const int blocks = (n + BT - 1) / BT;
  hipLaunchKernelGGL(fractal10, dim3(blocks), dim3(BT), 0, stream,
                     x, dpt, out, n, (const float*)ws);
  hipLaunchKernelGGL(fractal_generic, dim3(128), dim3(64), 0, stream, x, dpt, out, n,
                     (const float*)ws);
}

// Round 9
// 20.934 us; speedup vs baseline: 1.2490x; 1.2490x over previous
//
#include <hip/hip_runtime.h>

#define M 128
#define BT 64

typedef _Float16 half8 __attribute__((ext_vector_type(8)));
typedef __fp16 fp16x2 __attribute__((ext_vector_type(2)));
typedef float f32x4 __attribute__((ext_vector_type(4)));

// d_ws float layout (only what consumers actually read):
//   [0    .. 63]    prefix T tables: T_d at ws[2^d], size 2^d, d=0..5 (ws[0] = 0)
//   [3072 .. 3583]  sp/vals/li/ri for generic fallback
//   [4096 .. 5119]  A-fragment buffer: 4 frags x 64 lanes x 16B (f16, MFMA layout)
//
// A-matrix (Bt, 32x64): Bt[prow][i] :=
//   prow 0      -> T6[i]
//   prow 1..2   -> T7[2i+(prow-1)]
//   prow 3..6   -> T8[4i+(prow-3)]
//   prow 7..14  -> T9[8i+(prow-7)]
//   prow 15..30 -> V10[16i+(prow-15)]
//   prow 31     -> 0

__global__ void setup_kernel(const float* __restrict__ spp,
                             const float* __restrict__ vp,
                             const float* __restrict__ Lm,
                             const float* __restrict__ Rm,
                             float* __restrict__ ws) {
  __shared__ float ssp[M], svl[M];
  __shared__ int sli[M], sri[M];
  __shared__ float sT[1024];   // T_d at sT[2^d + i], d=0..9
  __shared__ float sV10[1024]; // V10[i]
  __shared__ int cur[1024], nxt[1024];
  const int t = threadIdx.x;   // 256 threads
  if (t < M) {
    ssp[t] = 1.f / (1.f + __expf(2.f - 4.f * spp[t]));
    svl[t] = vp[t & 31] * 3.f + 1.f;
  }
  {
    // flat coalesced one-hot scan: thread t owns 64 consecutive floats of
    // each matrix (16 float4, coalesced across the wave); the single nonzero
    // of each row is found by exactly one thread and scattered to LDS.
    const int base = t * 64;
    const float4* L4 = (const float4*)(Lm + base);
    const float4* R4 = (const float4*)(Rm + base);
#pragma unroll
    for (int j4 = 0; j4 < 16; ++j4) {
      const float4 lv = L4[j4];
      const float4 rv = R4[j4];
      const int f = base + 4 * j4;
#pragma unroll
      for (int e = 0; e < 4; ++e) {
        const float le = (e == 0) ? lv.x : (e == 1) ? lv.y : (e == 2) ? lv.z : lv.w;
        const float re = (e == 0) ? rv.x : (e == 1) ? rv.y : (e == 2) ? rv.z : rv.w;
        if (le > 0.5f) sli[(f + e) >> 7] = (f + e) & (M - 1);
        if (re > 0.5f) sri[(f + e) >> 7] = (f + e) & (M - 1);
      }
    }
  }
  if (t == 0) { cur[0] = 0; sT[0] = 0.f; }
  __syncthreads();
  if (t < M) {
    ws[3072 + t] = ssp[t];
    ws[3200 + t] = svl[t];
    ((int*)ws)[3328 + t] = sli[t];
    ((int*)ws)[3456 + t] = sri[t];
  }
  // pointer-chase table build, fully in LDS (level-parallel, 21 barriers)
  int S = 1;
  for (int d = 0; d <= 10; ++d) {
    for (int i = t; i < S; i += 256) {
      const int nd = cur[i];
      if (d <= 9) sT[S + i] = ssp[nd];
      else sV10[i] = svl[nd];
      if (d < 10) { nxt[2 * i] = sli[nd]; nxt[2 * i + 1] = sri[nd]; }
    }
    __syncthreads();
    if (d < 10) {
      for (int i = t; i < 2 * S; i += 256) cur[i] = nxt[i];
      __syncthreads();
    }
    S <<= 1;
  }
  // Build pre-packed f16 A-fragments from LDS. Element e of a lane's 16B frag
  // holds k-local kl = (e<4) ? 4g+e : 16+4g+(e-4); i = ks*32 + kl. The same
  // convention packs the B operand in fractal10, so the HW k-slot mapping
  // cancels regardless of its exact (g,e)->k bijection.
  unsigned* fbout = (unsigned*)(ws + 4096);
  for (int d = t; d < 1024; d += 256) {
    const int dw = d & 3;
    const int lane = (d >> 2) & 63;
    const int rt = d >> 9;
    const int ks = (d >> 8) & 1;
    const int m = lane & 15, gg = lane >> 4;
    const int prow = rt * 16 + m;
    float v[2];
#pragma unroll
    for (int h = 0; h < 2; ++h) {
      const int e = 2 * dw + h;
      const int kl = (e < 4) ? (4 * gg + e) : (16 + 4 * gg + (e - 4));
      const int i = ks * 32 + kl;
      float val;
      if (prow == 0) val = sT[64 + i];
      else if (prow < 3) val = sT[128 + 2 * i + (prow - 1)];
      else if (prow < 7) val = sT[256 + 4 * i + (prow - 3)];
      else if (prow < 15) val = sT[512 + 8 * i + (prow - 7)];
      else if (prow < 31) val = sV10[16 * i + (prow - 15)];
      else val = 0.f;
      v[h] = val;
    }
    union { fp16x2 h; unsigned u; } pu;
    pu.h = __builtin_amdgcn_cvt_pkrtz(v[0], v[1]);
    fbout[d] = pu.u;
  }
  // prefix tables T_0..T_5 for fractal10's register phase
  if (t < 64) ws[t] = sT[t];
}

#define PSTEP(S)                                                              \
  {                                                                           \
    float dot = 0.f;                                                          \
    _Pragma("unroll") for (int i = 0; i < (S); ++i)                           \
        dot = fmaf(c[i], sT[(S) + i], dot);                                   \
    const float sv = fmaf(dot, hi - lo, lo);                                  \
    tt = 1.f / (1.f + __expf((sv - xv) * 10.f));                              \
    uu = 1.f - tt;                                                            \
    const float nlo = fmaf(tt, sv, uu * lo);                                  \
    const float nhi = fmaf(tt, hi, uu * sv);                                  \
    lo = nlo; hi = nhi;                                                       \
    _Pragma("unroll") for (int i = (S)-1; i >= 0; --i) {                      \
      const float v = c[i];                                                   \
      c[2 * i + 1] = v * tt;                                                  \
      c[2 * i] = v * uu;                                                      \
    }                                                                         \
  }

#define SIGSTEP(dotv)                                   \
  {                                                     \
    const float sv = fmaf((dotv), hi - lo, lo);         \
    tt = 1.f / (1.f + __expf((sv - xv) * 10.f));        \
    uu = 1.f - tt;                                      \
    const float nlo = fmaf(tt, sv, uu * lo);            \
    const float nhi = fmaf(tt, hi, uu * sv);            \
    lo = nlo; hi = nhi;                                 \
  }

__launch_bounds__(BT)
__global__ void fractal10(const float* __restrict__ x,
                          const int* __restrict__ dpt,
                          float* __restrict__ out, int n,
                          const float* __restrict__ ws) {
  if (dpt[0] != 10) return;
  __shared__ float sT[64];
  __shared__ __align__(16) float sbuf[64 * 32];  // 8KB: c(f16) then P(f32), per point 128B
  const int l = threadIdx.x;
  const int gid = blockIdx.x * BT + l;

  sT[l] = ws[l];
  const float4* fb = (const float4*)(ws + 4096);
  union f4h8 { float4 f; half8 h; };
  f4h8 A00, A01, A10, A11;
  A00.f = fb[0 * 64 + l];   // rt0 ks0
  A01.f = fb[1 * 64 + l];   // rt0 ks1
  A10.f = fb[2 * 64 + l];   // rt1 ks0
  A11.f = fb[3 * 64 + l];   // rt1 ks1
  const float xv = (gid < n) ? x[gid] : 0.5f;
  __syncthreads();

  float c[64];
  float lo = 0.f, hi = 1.f, tt, uu;
  c[0] = 1.f;
  PSTEP(1) PSTEP(2) PSTEP(4) PSTEP(8) PSTEP(16) PSTEP(32)

  // pack c -> f16, write [point][chunk] with XOR-16B swizzle
  {
    char* cb = (char*)sbuf + l * 128;
#pragma unroll
    for (int q = 0; q < 8; ++q) {
      const int k0 = (q >> 2) * 32 + (q & 3) * 4;
      union { fp16x2 h2[4]; float4 f4; } u;
      u.h2[0] = __builtin_amdgcn_cvt_pkrtz(c[k0], c[k0 + 1]);
      u.h2[1] = __builtin_amdgcn_cvt_pkrtz(c[k0 + 2], c[k0 + 3]);
      u.h2[2] = __builtin_amdgcn_cvt_pkrtz(c[k0 + 16], c[k0 + 17]);
      u.h2[3] = __builtin_amdgcn_cvt_pkrtz(c[k0 + 18], c[k0 + 19]);
      *(float4*)(cb + ((q ^ (l & 7)) * 16)) = u.f4;
    }
  }
  __syncthreads();

  // read B fragments (transposed c)
  half8 bf[2][4];
  const int col = l & 15, g = l >> 4;
#pragma unroll
  for (int ct = 0; ct < 4; ++ct) {
    const int p = 16 * ct + col;
    const char* pb = (const char*)sbuf + p * 128;
#pragma unroll
    for (int ks = 0; ks < 2; ++ks) {
      const int q = ks * 4 + g;
      bf[ks][ct] = *(const half8*)(pb + ((q ^ (p & 7)) * 16));
    }
  }
  __syncthreads();

  // P[32 x 64pts] = Bt(32x64) x C(64x64)
  f32x4 acc[2][4];
#pragma unroll
  for (int rt = 0; rt < 2; ++rt)
#pragma unroll
    for (int ct = 0; ct < 4; ++ct) acc[rt][ct] = f32x4{0.f, 0.f, 0.f, 0.f};
#pragma unroll
  for (int ct = 0; ct < 4; ++ct) {
    acc[0][ct] = __builtin_amdgcn_mfma_f32_16x16x32_f16(A00.h, bf[0][ct], acc[0][ct], 0, 0, 0);
    acc[0][ct] = __builtin_amdgcn_mfma_f32_16x16x32_f16(A01.h, bf[1][ct], acc[0][ct], 0, 0, 0);
    acc[1][ct] = __builtin_amdgcn_mfma_f32_16x16x32_f16(A10.h, bf[0][ct], acc[1][ct], 0, 0, 0);
    acc[1][ct] = __builtin_amdgcn_mfma_f32_16x16x32_f16(A11.h, bf[1][ct], acc[1][ct], 0, 0, 0);
  }

  // scatter P back: D layout col=lane&15, row=(lane>>4)*4+reg (m89-verified)
#pragma unroll
  for (int rt = 0; rt < 2; ++rt)
#pragma unroll
    for (int ct = 0; ct < 4; ++ct) {
      const int p = 16 * ct + col;
      const int rb = rt * 4 + g;
      *(f32x4*)((char*)sbuf + p * 128 + ((rb ^ (p & 7)) * 16)) = acc[rt][ct];
    }
  __syncthreads();
  float4 P[8];
#pragma unroll
  for (int j = 0; j < 8; ++j)
    P[j] = *(const float4*)((const char*)sbuf + l * 128 + ((j ^ (l & 7)) * 16));

  // sequential tail on P: rows 0 | 1..2 | 3..6 | 7..14 | 15..30
  SIGSTEP(P[0].x);
  const float w20 = uu, w21 = tt;
  SIGSTEP(fmaf(w20, P[0].y, w21 * P[0].z));
  float W4[4] = {w20 * uu, w20 * tt, w21 * uu, w21 * tt};
  SIGSTEP(fmaf(W4[0], P[0].w, fmaf(W4[1], P[1].x, fmaf(W4[2], P[1].y, W4[3] * P[1].z))));
  float W8[8];
#pragma unroll
  for (int s = 3; s >= 0; --s) { W8[2 * s + 1] = W4[s] * tt; W8[2 * s] = W4[s] * uu; }
  {
    float d0 = fmaf(W8[0], P[1].w, W8[1] * P[2].x);
    float d1 = fmaf(W8[2], P[2].y, W8[3] * P[2].z);
    float d2 = fmaf(W8[4], P[2].w, W8[5] * P[3].x);
    float d3 = fmaf(W8[6], P[3].y, W8[7] * P[3].z);
    SIGSTEP((d0 + d1) + (d2 + d3));
  }
  float W16[16];
#pragma unroll
  for (int s = 7; s >= 0; --s) { W16[2 * s + 1] = W8[s] * tt; W16[2 * s] = W8[s] * uu; }
  float outv;
  {
    float d0 = fmaf(W16[0], P[3].w, W16[1] * P[4].x);
    d0 = fmaf(W16[2], P[4].y, d0); d0 = fmaf(W16[3], P[4].z, d0);
    float d1 = fmaf(W16[4], P[4].w, W16[5] * P[5].x);
    d1 = fmaf(W16[6], P[5].y, d1); d1 = fmaf(W16[7], P[5].z, d1);
    float d2 = fmaf(W16[8], P[5].w, W16[9] * P[6].x);
    d2 = fmaf(W16[10], P[6].y, d2); d2 = fmaf(W16[11], P[6].z, d2);
    float d3 = fmaf(W16[12], P[6].w, W16[13] * P[7].x);
    d3 = fmaf(W16[14], P[7].y, d3); d3 = fmaf(W16[15], P[7].z, d3);
    outv = (d0 + d1) + (d2 + d3);
  }
  if (gid < n) out[gid] = outv;
}

// Generic-depth fallback (never taken when depth==10; correctness only).
// LDS-backed [node][tid] state, column-per-thread => no scratch, no barriers.
__launch_bounds__(64)
__global__ void fractal_generic(const float* __restrict__ x,
                                const int* __restrict__ dpt,
                                float* __restrict__ out, int n,
                                const float* __restrict__ ws) {
  const int depth = dpt[0];
  if (depth == 10) return;
  __shared__ float w[2][M][64];  // 64KB
  const int t = threadIdx.x;
  const float* sp = ws + 3072;
  const float* vals = ws + 3200;
  const int* li = (const int*)ws + 3328;
  const int* ri = (const int*)ws + 3456;
  for (int gid = blockIdx.x * 64 + t; gid < n; gid += gridDim.x * 64) {
    const float xv = x[gid];
    for (int j = 0; j < M; ++j) w[0][j][t] = 0.f;
    w[0][0][t] = 1.f;
    float lo = 0.f, hi = 1.f;
    int cb = 0;
    for (int k = 0; k < depth; ++k) {
      float dot = 0.f;
      for (int j = 0; j < M; ++j) dot += w[cb][j][t] * sp[j];
      const float sv = lo + dot * (hi - lo);
      const float tt = 1.f / (1.f + __expf((sv - xv) * 10.f));
      const float uu = 1.f - tt;
      for (int j = 0; j < M; ++j) w[cb ^ 1][j][t] = 0.f;
      for (int j = 0; j < M; ++j) {
        const float v = w[cb][j][t];
        w[cb ^ 1][li[j]][t] += uu * v;
        w[cb ^ 1][ri[j]][t] += tt * v;
      }
      const float nlo = uu * lo + tt * sv;
      const float nhi = uu * sv + tt * hi;
      lo = nlo; hi = nhi;
      cb ^= 1;
    }
    float acc = 0.f;
    for (int j = 0; j < M; ++j) acc += w[cb][j][t] * vals[j];
    out[gid] = acc;
  }
}

extern "C" void kernel_launch(void* const* d_in, const int* in_sizes, int n_in,
                              void* d_out, int out_size, void* d_ws, size_t ws_size,
                              hipStream_t stream) {
  const float* x   = (const float*)d_in[0];
  const float* spp = (const float*)d_in[1];
  const float* vp  = (const float*)d_in[2];
  const float* Lm  = (const float*)d_in[3];
  const float* Rm  = (const float*)d_in[4];
  const int* dpt   = (const int*)d_in[5];
  float* out = (float*)d_out;
  float* ws = (float*)d_ws;
  const int n = in_sizes[0];

  hipLaunchKernelGGL(setup_kernel, dim3(1), dim3(256), 0, stream, spp, vp, Lm, Rm, ws);
  const int blocks = (n + BT - 1) / BT;
  hipLaunchKernelGGL(fractal10, dim3(blocks), dim3(BT), 0, stream,
                     x, dpt, out, n, (const float*)ws);
  hipLaunchKernelGGL(fractal_generic, dim3(128), dim3(64), 0, stream, x, dpt, out, n,
                     (const float*)ws);
}

// Round 10
// 19.392 us; speedup vs baseline: 1.3484x; 1.0796x over previous
//
#include <hip/hip_runtime.h>

#define M 128
#define BT 64

typedef _Float16 half8 __attribute__((ext_vector_type(8)));
typedef __fp16 fp16x2 __attribute__((ext_vector_type(2)));
typedef float f32x4 __attribute__((ext_vector_type(4)));

// d_ws float layout (only what consumers actually read):
//   [0    .. 63]    prefix T tables: T_d at ws[2^d], size 2^d, d=0..5 (ws[0] = 0)
//   [3072 .. 3583]  sp/vals/li/ri for generic fallback
//   [4096 .. 5119]  A-fragment buffer: 4 frags x 64 lanes x 16B (f16, MFMA layout)
//
// A-matrix (Bt, 32x64): Bt[prow][i] :=
//   prow 0 -> T6[i] | 1..2 -> T7[2i+..] | 3..6 -> T8[4i+..] | 7..14 -> T9[8i+..]
//   | 15..30 -> V10[16i+..] | 31 -> 0

__global__ void setup_kernel(const float* __restrict__ spp,
                             const float* __restrict__ vp,
                             const float* __restrict__ Lm,
                             const float* __restrict__ Rm,
                             float* __restrict__ ws) {
  __shared__ float ssp[M], svl[M];
  __shared__ int sli[M], sri[M];
  __shared__ int node6[64];
  __shared__ float sT[1024];   // T_d at sT[2^d + i], d=0..9
  __shared__ float sV10[1024]; // V10[i]
  const int t = threadIdx.x;   // 256 threads
  if (t < M) {
    ssp[t] = 1.f / (1.f + __expf(2.f - 4.f * spp[t]));
    svl[t] = vp[t & 31] * 3.f + 1.f;
  }
  {
    // truly coalesced one-hot scan: lane-consecutive float4s (16/thread/matrix)
    const float4* L4 = (const float4*)Lm;
    const float4* R4 = (const float4*)Rm;
#pragma unroll
    for (int k = 0; k < 16; ++k) {
      const int v = t + 256 * k;   // float4 index; row = v>>5 (32 float4/row)
      const float4 lv = L4[v];
      const float4 rv = R4[v];
      const int row = v >> 5;
      const int c0 = (v & 31) * 4;
      if (lv.x > 0.5f) sli[row] = c0;
      if (lv.y > 0.5f) sli[row] = c0 + 1;
      if (lv.z > 0.5f) sli[row] = c0 + 2;
      if (lv.w > 0.5f) sli[row] = c0 + 3;
      if (rv.x > 0.5f) sri[row] = c0;
      if (rv.y > 0.5f) sri[row] = c0 + 1;
      if (rv.z > 0.5f) sri[row] = c0 + 2;
      if (rv.w > 0.5f) sri[row] = c0 + 3;
    }
  }
  __syncthreads();  // B1: sli/sri/ssp/svl ready
  if (t < M) {
    ws[3072 + t] = ssp[t];
    ws[3200 + t] = svl[t];
    ((int*)ws)[3328 + t] = sli[t];
    ((int*)ws)[3456 + t] = sri[t];
  }
  if (t == 0) { sT[0] = 0.f; sT[1] = ssp[0]; }
  if (t < 64) {
    // wave 0: prefix chase d=1..6 for 6-bit index t (MSB = first step)
    int nd = 0;
#pragma unroll
    for (int d = 1; d <= 6; ++d) {
      const int sh = 6 - d;
      const int bit = (t >> sh) & 1;
      nd = bit ? sri[nd] : sli[nd];
      if ((t & ((1 << sh) - 1)) == 0) sT[(1 << d) + (t >> sh)] = ssp[nd];
    }
    node6[t] = nd;
  }
  __syncthreads();  // B2: node6 + T1..T6 ready
  {
    // leaf expansion: thread t covers paths p = 4t..4t+3 (prefix6 = t>>2)
    const int n6 = node6[t >> 2];
    const int b7 = (t >> 1) & 1;
    const int nd7 = b7 ? sri[n6] : sli[n6];
    const int b8 = t & 1;
    const int nd8 = b8 ? sri[nd7] : sli[nd7];
    if (!b8) sT[128 + (t >> 1)] = ssp[nd7];  // T7[p>>3], once (t even)
    sT[256 + t] = ssp[nd8];                  // T8[t]
    const int nd90 = sli[nd8];
    const int nd91 = sri[nd8];
    sT[512 + 2 * t] = ssp[nd90];             // T9[2t]
    sT[512 + 2 * t + 1] = ssp[nd91];         // T9[2t+1]
    sV10[4 * t + 0] = svl[sli[nd90]];
    sV10[4 * t + 1] = svl[sri[nd90]];
    sV10[4 * t + 2] = svl[sli[nd91]];
    sV10[4 * t + 3] = svl[sri[nd91]];
  }
  __syncthreads();  // B3: all tables ready

  // Build pre-packed f16 A-fragments from LDS. Element e of a lane's 16B frag
  // holds k-local kl = (e<4) ? 4g+e : 16+4g+(e-4); i = ks*32 + kl. The same
  // convention packs the B operand in fractal10, so the HW k-slot mapping
  // cancels regardless of its exact (g,e)->k bijection.
  unsigned* fbout = (unsigned*)(ws + 4096);
  for (int d = t; d < 1024; d += 256) {
    const int dw = d & 3;
    const int lane = (d >> 2) & 63;
    const int rt = d >> 9;
    const int ks = (d >> 8) & 1;
    const int m = lane & 15, gg = lane >> 4;
    const int prow = rt * 16 + m;
    float v[2];
#pragma unroll
    for (int h = 0; h < 2; ++h) {
      const int e = 2 * dw + h;
      const int kl = (e < 4) ? (4 * gg + e) : (16 + 4 * gg + (e - 4));
      const int i = ks * 32 + kl;
      float val;
      if (prow == 0) val = sT[64 + i];
      else if (prow < 3) val = sT[128 + 2 * i + (prow - 1)];
      else if (prow < 7) val = sT[256 + 4 * i + (prow - 3)];
      else if (prow < 15) val = sT[512 + 8 * i + (prow - 7)];
      else if (prow < 31) val = sV10[16 * i + (prow - 15)];
      else val = 0.f;
      v[h] = val;
    }
    union { fp16x2 h; unsigned u; } pu;
    pu.h = __builtin_amdgcn_cvt_pkrtz(v[0], v[1]);
    fbout[d] = pu.u;
  }
  // prefix tables T_0..T_5 for fractal10's register phase
  if (t < 64) ws[t] = sT[t];
}

#define PSTEP(S)                                                              \
  {                                                                           \
    float dot = 0.f;                                                          \
    _Pragma("unroll") for (int i = 0; i < (S); ++i)                           \
        dot = fmaf(c[i], sT[(S) + i], dot);                                   \
    const float sv = fmaf(dot, hi - lo, lo);                                  \
    tt = 1.f / (1.f + __expf((sv - xv) * 10.f));                              \
    uu = 1.f - tt;                                                            \
    const float nlo = fmaf(tt, sv, uu * lo);                                  \
    const float nhi = fmaf(tt, hi, uu * sv);                                  \
    lo = nlo; hi = nhi;                                                       \
    _Pragma("unroll") for (int i = (S)-1; i >= 0; --i) {                      \
      const float v = c[i];                                                   \
      c[2 * i + 1] = v * tt;                                                  \
      c[2 * i] = v * uu;                                                      \
    }                                                                         \
  }

#define SIGSTEP(dotv)                                   \
  {                                                     \
    const float sv = fmaf((dotv), hi - lo, lo);         \
    tt = 1.f / (1.f + __expf((sv - xv) * 10.f));        \
    uu = 1.f - tt;                                      \
    const float nlo = fmaf(tt, sv, uu * lo);            \
    const float nhi = fmaf(tt, hi, uu * sv);            \
    lo = nlo; hi = nhi;                                 \
  }

__launch_bounds__(BT)
__global__ void fractal10(const float* __restrict__ x,
                          const int* __restrict__ dpt,
                          float* __restrict__ out, int n,
                          const float* __restrict__ ws) {
  if (dpt[0] != 10) return;
  __shared__ float sT[64];
  __shared__ __align__(16) float sbuf[64 * 32];  // 8KB: c(f16) then P(f32), per point 128B
  const int l = threadIdx.x;
  const int gid = blockIdx.x * BT + l;

  sT[l] = ws[l];
  const float4* fb = (const float4*)(ws + 4096);
  union f4h8 { float4 f; half8 h; };
  f4h8 A00, A01, A10, A11;
  A00.f = fb[0 * 64 + l];   // rt0 ks0
  A01.f = fb[1 * 64 + l];   // rt0 ks1
  A10.f = fb[2 * 64 + l];   // rt1 ks0
  A11.f = fb[3 * 64 + l];   // rt1 ks1
  const float xv = (gid < n) ? x[gid] : 0.5f;
  __syncthreads();

  float c[64];
  float lo = 0.f, hi = 1.f, tt, uu;
  c[0] = 1.f;
  PSTEP(1) PSTEP(2) PSTEP(4) PSTEP(8) PSTEP(16) PSTEP(32)

  // pack c -> f16, write [point][chunk] with XOR-16B swizzle
  {
    char* cb = (char*)sbuf + l * 128;
#pragma unroll
    for (int q = 0; q < 8; ++q) {
      const int k0 = (q >> 2) * 32 + (q & 3) * 4;
      union { fp16x2 h2[4]; float4 f4; } u;
      u.h2[0] = __builtin_amdgcn_cvt_pkrtz(c[k0], c[k0 + 1]);
      u.h2[1] = __builtin_amdgcn_cvt_pkrtz(c[k0 + 2], c[k0 + 3]);
      u.h2[2] = __builtin_amdgcn_cvt_pkrtz(c[k0 + 16], c[k0 + 17]);
      u.h2[3] = __builtin_amdgcn_cvt_pkrtz(c[k0 + 18], c[k0 + 19]);
      *(float4*)(cb + ((q ^ (l & 7)) * 16)) = u.f4;
    }
  }
  __syncthreads();

  // read B fragments (transposed c)
  half8 bf[2][4];
  const int col = l & 15, g = l >> 4;
#pragma unroll
  for (int ct = 0; ct < 4; ++ct) {
    const int p = 16 * ct + col;
    const char* pb = (const char*)sbuf + p * 128;
#pragma unroll
    for (int ks = 0; ks < 2; ++ks) {
      const int q = ks * 4 + g;
      bf[ks][ct] = *(const half8*)(pb + ((q ^ (p & 7)) * 16));
    }
  }
  __syncthreads();

  // P[32 x 64pts] = Bt(32x64) x C(64x64)
  f32x4 acc[2][4];
#pragma unroll
  for (int rt = 0; rt < 2; ++rt)
#pragma unroll
    for (int ct = 0; ct < 4; ++ct) acc[rt][ct] = f32x4{0.f, 0.f, 0.f, 0.f};
#pragma unroll
  for (int ct = 0; ct < 4; ++ct) {
    acc[0][ct] = __builtin_amdgcn_mfma_f32_16x16x32_f16(A00.h, bf[0][ct], acc[0][ct], 0, 0, 0);
    acc[0][ct] = __builtin_amdgcn_mfma_f32_16x16x32_f16(A01.h, bf[1][ct], acc[0][ct], 0, 0, 0);
    acc[1][ct] = __builtin_amdgcn_mfma_f32_16x16x32_f16(A10.h, bf[0][ct], acc[1][ct], 0, 0, 0);
    acc[1][ct] = __builtin_amdgcn_mfma_f32_16x16x32_f16(A11.h, bf[1][ct], acc[1][ct], 0, 0, 0);
  }

  // scatter P back: D layout col=lane&15, row=(lane>>4)*4+reg (m89-verified)
#pragma unroll
  for (int rt = 0; rt < 2; ++rt)
#pragma unroll
    for (int ct = 0; ct < 4; ++ct) {
      const int p = 16 * ct + col;
      const int rb = rt * 4 + g;
      *(f32x4*)((char*)sbuf + p * 128 + ((rb ^ (p & 7)) * 16)) = acc[rt][ct];
    }
  __syncthreads();
  float4 P[8];
#pragma unroll
  for (int j = 0; j < 8; ++j)
    P[j] = *(const float4*)((const char*)sbuf + l * 128 + ((j ^ (l & 7)) * 16));

  // sequential tail on P: rows 0 | 1..2 | 3..6 | 7..14 | 15..30
  SIGSTEP(P[0].x);
  const float w20 = uu, w21 = tt;
  SIGSTEP(fmaf(w20, P[0].y, w21 * P[0].z));
  float W4[4] = {w20 * uu, w20 * tt, w21 * uu, w21 * tt};
  SIGSTEP(fmaf(W4[0], P[0].w, fmaf(W4[1], P[1].x, fmaf(W4[2], P[1].y, W4[3] * P[1].z))));
  float W8[8];
#pragma unroll
  for (int s = 3; s >= 0; --s) { W8[2 * s + 1] = W4[s] * tt; W8[2 * s] = W4[s] * uu; }
  {
    float d0 = fmaf(W8[0], P[1].w, W8[1] * P[2].x);
    float d1 = fmaf(W8[2], P[2].y, W8[3] * P[2].z);
    float d2 = fmaf(W8[4], P[2].w, W8[5] * P[3].x);
    float d3 = fmaf(W8[6], P[3].y, W8[7] * P[3].z);
    SIGSTEP((d0 + d1) + (d2 + d3));
  }
  float W16[16];
#pragma unroll
  for (int s = 7; s >= 0; --s) { W16[2 * s + 1] = W8[s] * tt; W16[2 * s] = W8[s] * uu; }
  float outv;
  {
    float d0 = fmaf(W16[0], P[3].w, W16[1] * P[4].x);
    d0 = fmaf(W16[2], P[4].y, d0); d0 = fmaf(W16[3], P[4].z, d0);
    float d1 = fmaf(W16[4], P[4].w, W16[5] * P[5].x);
    d1 = fmaf(W16[6], P[5].y, d1); d1 = fmaf(W16[7], P[5].z, d1);
    float d2 = fmaf(W16[8], P[5].w, W16[9] * P[6].x);
    d2 = fmaf(W16[10], P[6].y, d2); d2 = fmaf(W16[11], P[6].z, d2);
    float d3 = fmaf(W16[12], P[6].w, W16[13] * P[7].x);
    d3 = fmaf(W16[14], P[7].y, d3); d3 = fmaf(W16[15], P[7].z, d3);
    outv = (d0 + d1) + (d2 + d3);
  }
  if (gid < n) out[gid] = outv;
}

// Generic-depth fallback (never taken when depth==10; correctness only).
// LDS-backed [node][tid] state, column-per-thread => no scratch, no barriers.
__launch_bounds__(64)
__global__ void fractal_generic(const float* __restrict__ x,
                                const int* __restrict__ dpt,
                                float* __restrict__ out, int n,
                                const float* __restrict__ ws) {
  const int depth = dpt[0];
  if (depth == 10) return;
  __shared__ float w[2][M][64];  // 64KB
  const int t = threadIdx.x;
  const float* sp = ws + 3072;
  const float* vals = ws + 3200;
  const int* li = (const int*)ws + 3328;
  const int* ri = (const int*)ws + 3456;
  for (int gid = blockIdx.x * 64 + t; gid < n; gid += gridDim.x * 64) {
    const float xv = x[gid];
    for (int j = 0; j < M; ++j) w[0][j][t] = 0.f;
    w[0][0][t] = 1.f;
    float lo = 0.f, hi = 1.f;
    int cb = 0;
    for (int k = 0; k < depth; ++k) {
      float dot = 0.f;
      for (int j = 0; j < M; ++j) dot += w[cb][j][t] * sp[j];
      const float sv = lo + dot * (hi - lo);
      const float tt = 1.f / (1.f + __expf((sv - xv) * 10.f));
      const float uu = 1.f - tt;
      for (int j = 0; j < M; ++j) w[cb ^ 1][j][t] = 0.f;
      for (int j = 0; j < M; ++j) {
        const float v = w[cb][j][t];
        w[cb ^ 1][li[j]][t] += uu * v;
        w[cb ^ 1][ri[j]][t] += tt * v;
      }
      const float nlo = uu * lo + tt * sv;
      const float nhi = uu * sv + tt * hi;
      lo = nlo; hi = nhi;
      cb ^= 1;
    }
    float acc = 0.f;
    for (int j = 0; j < M; ++j) acc += w[cb][j][t] * vals[j];
    out[gid] = acc;
  }
}

extern "C" void kernel_launch(void* const* d_in, const int* in_sizes, int n_in,
                              void* d_out, int out_size, void* d_ws, size_t ws_size,
                              hipStream_t stream) {
  const float* x   = (const float*)d_in[0];
  const float* spp = (const float*)d_in[1];
  const float* vp  = (const float*)d_in[2];
  const float* Lm  = (const float*)d_in[3];
  const float* Rm  = (const float*)d_in[4];
  const int* dpt   = (const int*)d_in[5];
  float* out = (float*)d_out;
  float* ws = (float*)d_ws;
  const int n = in_sizes[0];

  hipLaunchKernelGGL(setup_kernel, dim3(1), dim3(256), 0, stream, spp, vp, Lm, Rm, ws);
  const int blocks = (n + BT - 1) / BT;
  hipLaunchKernelGGL(fractal10, dim3(blocks), dim3(BT), 0, stream,
                     x, dpt, out, n, (const float*)ws);
  hipLaunchKernelGGL(fractal_generic, dim3(128), dim3(64), 0, stream, x, dpt, out, n,
                     (const float*)ws);
}